// Round 1
// baseline (15904.189 us; speedup 1.0000x reference)
//
#include <hip/hip_runtime.h>

typedef _Float16 half8 __attribute__((ext_vector_type(8)));
typedef float float4v __attribute__((ext_vector_type(4)));

#define BATCH   128
#define HID     512
#define DIN     128

// LDS layout (bytes). x: 8 rows x 132 floats (pad 4). h: 8 rows x 520 halves (pad 8).
#define X_STRIDE 132
#define H_STRIDE 520
#define HOFF (8 * X_STRIDE * 4)            // 4224
#define GOFF (HOFF + 8 * H_STRIDE * 2)     // 12544
#define LDS_BYTES (GOFF + 4 * 8 * 32 * 4)  // + per-wave gate scratch = 16640

__device__ inline half8 cvt8(float4v a, float4v b) {
    half8 r;
    r[0] = (_Float16)a[0]; r[1] = (_Float16)a[1];
    r[2] = (_Float16)a[2]; r[3] = (_Float16)a[3];
    r[4] = (_Float16)b[0]; r[5] = (_Float16)b[1];
    r[6] = (_Float16)b[2]; r[7] = (_Float16)b[3];
    return r;
}

__device__ inline float sigm(float x) { return 1.0f / (1.0f + __expf(-x)); }

// 16 teams x 16 CUs. Team t = blockIdx&15 owns rows [8t, 8t+8); CU p = blockIdx>>4
// owns hidden units [32p, 32p+32); wave w owns units [32p+8w, 32p+8w+8).
// w_hh/w_ih fragments are VGPR-resident fp16 for the whole kernel.
__global__ __launch_bounds__(256, 1)
void lstm_persistent(const int* __restrict__ ids,
                     const int* __restrict__ seq_len,
                     const float* __restrict__ emb,
                     const float* __restrict__ w_ih,
                     const float* __restrict__ w_hh,
                     const float* __restrict__ b_ih,
                     const float* __restrict__ b_hh,
                     float* __restrict__ out,
                     _Float16* __restrict__ h_buf,   // [2][128][512] fp16 in d_ws
                     int* __restrict__ flags)        // [16][16] ints in d_ws
{
    __shared__ __align__(16) char smem[LDS_BYTES];
    float*    xs = (float*)(smem);
    _Float16* hs = (_Float16*)(smem + HOFF);
    float*    gs = (float*)(smem + GOFF);

    const int tid  = threadIdx.x;
    const int lane = tid & 63;
    const int wv   = tid >> 6;
    const int team = blockIdx.x & 15;   // blockIdx%16: team members share XCD (b%8)
    const int p    = blockIdx.x >> 4;
    const int rowbase   = team * 8;
    const int unit_base = p * 32 + wv * 8;

    const int col  = lane & 15;   // MFMA n / C col
    const int kq   = lane >> 4;   // MFMA k-quad
    const int arow = lane & 7;    // A row (rows 8..15 duplicate 0..7; C rows 8..15 ignored)
    const int my_row  = lane >> 3;        // owner cell: (row, unit)
    const int my_unit = unit_base + (lane & 7);

    // seq_len -> per-row snapshot step and team loop bound (uniform across team)
    int tmax = 0, my_tstar = 0;
    for (int r = 0; r < 8; ++r) {
        int s  = seq_len[rowbase + r];
        int ts = (s > 0) ? (s - 1) : 0;
        if (r == my_row) my_tstar = ts;
        tmax = (ts > tmax) ? ts : tmax;
    }

    // ---- load weight fragments into VGPRs (fp32 -> fp16), once ----
    // col c of n-tile n maps to (u_local = n*4 + (c>>2), gate = c&3); W row = gate*512 + unit.
    const int wrow0 = (col & 3) * (4 * HID / 4) + unit_base + (col >> 2);        // gate*512 + u (n=0)
    const int wrow1 = (col & 3) * (4 * HID / 4) + unit_base + 4 + (col >> 2);    // n=1
    const float bias0 = b_ih[wrow0] + b_hh[wrow0];
    const float bias1 = b_ih[wrow1] + b_hh[wrow1];

    half8 whhf0[16], whhf1[16];
#pragma unroll
    for (int kt = 0; kt < 16; ++kt) {
        const float* s0 = w_hh + (size_t)wrow0 * HID + kt * 32 + kq * 8;
        const float* s1 = w_hh + (size_t)wrow1 * HID + kt * 32 + kq * 8;
        whhf0[kt] = cvt8(*(const float4v*)s0, *(const float4v*)(s0 + 4));
        whhf1[kt] = cvt8(*(const float4v*)s1, *(const float4v*)(s1 + 4));
    }
    half8 wihf0[4], wihf1[4];
#pragma unroll
    for (int kt = 0; kt < 4; ++kt) {
        const float* s0 = w_ih + (size_t)wrow0 * DIN + kt * 32 + kq * 8;
        const float* s1 = w_ih + (size_t)wrow1 * DIN + kt * 32 + kq * 8;
        wihf0[kt] = cvt8(*(const float4v*)s0, *(const float4v*)(s0 + 4));
        wihf1[kt] = cvt8(*(const float4v*)s1, *(const float4v*)(s1 + 4));
    }

    float c_state = 0.0f;
    const int crow = tid >> 5;    // staging: row 0..7
    const int coff = tid & 31;    // staging: 32 threads per row
    const int fi   = team * 16 + (lane & 15);

    for (int t = 0; t <= tmax; ++t) {
        // ---- embedding gather for step t (independent of h; overlaps the spin) ----
        const int id = ids[t * BATCH + rowbase + crow];
        const float4v xv = *(const float4v*)(emb + (size_t)id * DIN + coff * 4);

        // ---- wait for all 16 teammates to have published h(t-1) ----
        if (t > 0) {
            int guard = 0;
            for (;;) {
                int f = __hip_atomic_load(flags + fi, __ATOMIC_RELAXED,
                                          __HIP_MEMORY_SCOPE_AGENT);
                bool ok = (lane >= 16) | (f >= t);
                if (__ballot(ok) == ~0ull) break;
                if (++guard > 20000000) break;   // anti-hang safety valve
                __builtin_amdgcn_s_sleep(1);
            }
            __threadfence();   // agent acquire: invalidate L1/L2 before reading h
        }

        // ---- stage x (fp32) and h(t-1) (fp16) into padded LDS ----
        *(float4v*)(xs + crow * X_STRIDE + coff * 4) = xv;
        if (t > 0) {
            const _Float16* hsrc = h_buf + (size_t)((t + 1) & 1) * BATCH * HID
                                   + (rowbase + crow) * HID + coff * 16;
            uint4 h0 = *(const uint4*)hsrc;
            uint4 h1 = *(const uint4*)(hsrc + 8);
            *(uint4*)(hs + crow * H_STRIDE + coff * 16)     = h0;
            *(uint4*)(hs + crow * H_STRIDE + coff * 16 + 8) = h1;
        }
        __syncthreads();

        // ---- gates = bias + x @ w_ih^T + h @ w_hh^T  (fp32 accum, 4 chains) ----
        float4v acc0a = {bias0, bias0, bias0, bias0};
        float4v acc1a = {bias1, bias1, bias1, bias1};
        float4v acc0b = {0, 0, 0, 0}, acc1b = {0, 0, 0, 0};

#pragma unroll
        for (int kt = 0; kt < 4; ++kt) {
            const float* xsrc = xs + arow * X_STRIDE + kt * 32 + kq * 8;
            half8 af = cvt8(*(const float4v*)xsrc, *(const float4v*)(xsrc + 4));
            if (kt & 1) {
                acc0b = __builtin_amdgcn_mfma_f32_16x16x32_f16(af, wihf0[kt], acc0b, 0, 0, 0);
                acc1b = __builtin_amdgcn_mfma_f32_16x16x32_f16(af, wihf1[kt], acc1b, 0, 0, 0);
            } else {
                acc0a = __builtin_amdgcn_mfma_f32_16x16x32_f16(af, wihf0[kt], acc0a, 0, 0, 0);
                acc1a = __builtin_amdgcn_mfma_f32_16x16x32_f16(af, wihf1[kt], acc1a, 0, 0, 0);
            }
        }
        if (t > 0) {
#pragma unroll
            for (int kt = 0; kt < 16; ++kt) {
                half8 af = *(const half8*)(hs + arow * H_STRIDE + kt * 32 + kq * 8);
                if (kt & 1) {
                    acc0b = __builtin_amdgcn_mfma_f32_16x16x32_f16(af, whhf0[kt], acc0b, 0, 0, 0);
                    acc1b = __builtin_amdgcn_mfma_f32_16x16x32_f16(af, whhf1[kt], acc1b, 0, 0, 0);
                } else {
                    acc0a = __builtin_amdgcn_mfma_f32_16x16x32_f16(af, whhf0[kt], acc0a, 0, 0, 0);
                    acc1a = __builtin_amdgcn_mfma_f32_16x16x32_f16(af, whhf1[kt], acc1a, 0, 0, 0);
                }
            }
        }
        const float4v g0 = acc0a + acc0b;
        const float4v g1 = acc1a + acc1b;

        // ---- regroup i,f,g,o per (row,unit) via per-wave LDS scratch ----
        float* gw = gs + wv * 256;
        if (lane < 32) {             // C rows 0..7 live in lanes 0..31
            const int grow = (lane >> 4) * 4;
#pragma unroll
            for (int r = 0; r < 4; ++r) {
                gw[(grow + r) * 32 + col]      = g0[r];
                gw[(grow + r) * 32 + 16 + col] = g1[r];
            }
        }
        const float4v g4 = *(const float4v*)(gw + my_row * 32 + (lane & 7) * 4);

        const float i_s = sigm(g4[0]);
        const float f_s = sigm(g4[1]);
        const float g_t = tanhf(g4[2]);
        const float o_s = sigm(g4[3]);
        c_state = f_s * c_state + i_s * g_t;
        const float hn = o_s * tanhf(c_state);

        if (t == my_tstar)
            out[(rowbase + my_row) * HID + my_unit] = c_state;

        h_buf[(size_t)(t & 1) * BATCH * HID + (rowbase + my_row) * HID + my_unit] =
            (_Float16)hn;

        __syncthreads();             // drains vmcnt: all h stores issued to L2
        if (tid == 0)
            __hip_atomic_store(flags + team * 16 + p, t + 1, __ATOMIC_RELEASE,
                               __HIP_MEMORY_SCOPE_AGENT);
    }
}

extern "C" void kernel_launch(void* const* d_in, const int* in_sizes, int n_in,
                              void* d_out, int out_size, void* d_ws, size_t ws_size,
                              hipStream_t stream)
{
    const int*   ids  = (const int*)d_in[0];
    const int*   slen = (const int*)d_in[1];
    const float* emb  = (const float*)d_in[2];
    const float* wih  = (const float*)d_in[3];
    const float* whh  = (const float*)d_in[4];
    const float* bih  = (const float*)d_in[5];
    const float* bhh  = (const float*)d_in[6];
    float* out = (float*)d_out;

    _Float16* h_buf = (_Float16*)d_ws;                                  // 256 KiB
    int* flags = (int*)((char*)d_ws + 2 * BATCH * HID * sizeof(_Float16));

    hipLaunchKernelGGL(lstm_persistent, dim3(256), dim3(256), 0, stream,
                       ids, slen, emb, wih, whh, bih, bhh, out, h_buf, flags);
}

// Round 2
// 3158.186 us; speedup vs baseline: 5.0359x; 5.0359x over previous
//
#include <hip/hip_runtime.h>

typedef _Float16 half8 __attribute__((ext_vector_type(8)));
typedef float float4v __attribute__((ext_vector_type(4)));

#define BATCH   128
#define HID     512
#define DIN     128

// LDS layout: h tile 8 rows x 520 halves (pad 8 to break bank-stride), then
// per-wave gate scratch 4 x (8 rows x 32 floats).
#define H_STRIDE 520
#define GOFF (8 * H_STRIDE * 2)            // 8320
#define LDS_BYTES (GOFF + 4 * 8 * 32 * 4)  // 12416

__device__ inline half8 cvt8(float4v a, float4v b) {
    half8 r;
    r[0] = (_Float16)a[0]; r[1] = (_Float16)a[1];
    r[2] = (_Float16)a[2]; r[3] = (_Float16)a[3];
    r[4] = (_Float16)b[0]; r[5] = (_Float16)b[1];
    r[6] = (_Float16)b[2]; r[7] = (_Float16)b[3];
    return r;
}

__device__ inline float sigm(float x) { return 1.0f / (1.0f + __expf(-x)); }

// 16 teams x 16 CUs (team = blockIdx&15 -> teammates share blockIdx%8 -> XCD
// locality heuristic only; correctness is via LLC-level relaxed atomics).
// Team owns rows [8t,8t+8); CU p owns units [32p,32p+32); wave w units [..+8w ..).
// h handoff: tagged 32-bit words ((t+1)<<16 | fp16(h)), double-buffered in d_ws,
// relaxed AGENT atomics only -> NO buffer_wbl2 / buffer_inv in the step loop.
__global__ __launch_bounds__(256, 1)
void lstm_persistent(const int* __restrict__ ids,
                     const int* __restrict__ seq_len,
                     const float* __restrict__ emb,
                     const float* __restrict__ w_ih,
                     const float* __restrict__ w_hh,
                     const float* __restrict__ b_ih,
                     const float* __restrict__ b_hh,
                     float* __restrict__ out,
                     unsigned* __restrict__ h_words)   // [2][128][512] tagged words
{
    __shared__ __align__(16) char smem[LDS_BYTES];
    _Float16* hs  = (_Float16*)(smem);
    float*    gs  = (float*)(smem + GOFF);
    unsigned* hsu = (unsigned*)hs;

    const int tid  = threadIdx.x;
    const int lane = tid & 63;
    const int wv   = tid >> 6;
    const int team = blockIdx.x & 15;
    const int p    = blockIdx.x >> 4;
    const int rowbase   = team * 8;
    const int unit_base = p * 32 + wv * 8;

    const int col  = lane & 15;   // MFMA n / C col
    const int kq   = lane >> 4;   // MFMA k-quad
    const int arow = lane & 7;    // A row (rows 8..15 duplicate 0..7)
    const int my_row  = lane >> 3;
    const int my_unit = unit_base + (lane & 7);

    int tmax = 0, my_tstar = 0;
    for (int r = 0; r < 8; ++r) {
        int s  = seq_len[rowbase + r];
        int ts = (s > 0) ? (s - 1) : 0;
        if (r == my_row) my_tstar = ts;
        tmax = (ts > tmax) ? ts : tmax;
    }

    // ---- weight fragments -> VGPRs (fp32 -> fp16), once ----
    const int wrow0 = (col & 3) * HID + unit_base + (col >> 2);
    const int wrow1 = (col & 3) * HID + unit_base + 4 + (col >> 2);
    const float bias0 = b_ih[wrow0] + b_hh[wrow0];
    const float bias1 = b_ih[wrow1] + b_hh[wrow1];

    half8 whhf0[16], whhf1[16];
#pragma unroll
    for (int kt = 0; kt < 16; ++kt) {
        const float* s0 = w_hh + (size_t)wrow0 * HID + kt * 32 + kq * 8;
        const float* s1 = w_hh + (size_t)wrow1 * HID + kt * 32 + kq * 8;
        whhf0[kt] = cvt8(*(const float4v*)s0, *(const float4v*)(s0 + 4));
        whhf1[kt] = cvt8(*(const float4v*)s1, *(const float4v*)(s1 + 4));
    }
    half8 wihf0[4], wihf1[4];
#pragma unroll
    for (int kt = 0; kt < 4; ++kt) {
        const float* s0 = w_ih + (size_t)wrow0 * DIN + kt * 32 + kq * 8;
        const float* s1 = w_ih + (size_t)wrow1 * DIN + kt * 32 + kq * 8;
        wihf0[kt] = cvt8(*(const float4v*)s0, *(const float4v*)(s0 + 4));
        wihf1[kt] = cvt8(*(const float4v*)s1, *(const float4v*)(s1 + 4));
    }

    float c_state = 0.0f;
    const int crow = tid >> 5;    // staging: row 0..7, 32 threads/row
    const int coff = tid & 31;    // 16 units (8 b64 words) per thread

    for (int t = 0; t <= tmax; ++t) {
        // ---- x fragments straight from emb (cached; L2 is never invalidated) ----
        const int id = ids[t * BATCH + rowbase + arow];
        const float* xrow = emb + (size_t)id * DIN;

        float4v acc0a = {bias0, bias0, bias0, bias0};
        float4v acc1a = {bias1, bias1, bias1, bias1};
        float4v acc0b = {0, 0, 0, 0}, acc1b = {0, 0, 0, 0};

#pragma unroll
        for (int kt = 0; kt < 4; ++kt) {
            const float* xsrc = xrow + kt * 32 + kq * 8;
            half8 af = cvt8(*(const float4v*)xsrc, *(const float4v*)(xsrc + 4));
            if (kt & 1) {
                acc0b = __builtin_amdgcn_mfma_f32_16x16x32_f16(af, wihf0[kt], acc0b, 0, 0, 0);
                acc1b = __builtin_amdgcn_mfma_f32_16x16x32_f16(af, wihf1[kt], acc1b, 0, 0, 0);
            } else {
                acc0a = __builtin_amdgcn_mfma_f32_16x16x32_f16(af, wihf0[kt], acc0a, 0, 0, 0);
                acc1a = __builtin_amdgcn_mfma_f32_16x16x32_f16(af, wihf1[kt], acc1a, 0, 0, 0);
            }
        }

        if (t > 0) {
            // ---- poll teammates' tagged h words (the poll IS the data load) ----
            const unsigned long long* src = (const unsigned long long*)
                (h_words + (size_t)((t + 1) & 1) * BATCH * HID
                         + (rowbase + crow) * HID + coff * 16);
            const unsigned long long tagpat =
                ((unsigned long long)t << 16) | ((unsigned long long)t << 48);
            unsigned long long w[8];
            int guard = 0;
            for (;;) {
                bool ok = true;
#pragma unroll
                for (int j = 0; j < 8; ++j) {
                    w[j] = __hip_atomic_load(src + j, __ATOMIC_RELAXED,
                                             __HIP_MEMORY_SCOPE_AGENT);
                    ok &= ((w[j] & 0xFFFF0000FFFF0000ull) == tagpat);
                }
                if (ok) break;
                if (++guard > (1 << 24)) break;   // anti-hang safety valve
            }
            // unpack 16 fp16 into padded LDS tile
#pragma unroll
            for (int j = 0; j < 8; ++j) {
                unsigned packed = (unsigned)(w[j] & 0xFFFFu)
                                | ((unsigned)((w[j] >> 32) & 0xFFFFu) << 16);
                hsu[crow * (H_STRIDE / 2) + coff * 8 + j] = packed;
            }
            __syncthreads();

#pragma unroll
            for (int kt = 0; kt < 16; ++kt) {
                half8 af = *(const half8*)(hs + arow * H_STRIDE + kt * 32 + kq * 8);
                if (kt & 1) {
                    acc0b = __builtin_amdgcn_mfma_f32_16x16x32_f16(af, whhf0[kt], acc0b, 0, 0, 0);
                    acc1b = __builtin_amdgcn_mfma_f32_16x16x32_f16(af, whhf1[kt], acc1b, 0, 0, 0);
                } else {
                    acc0a = __builtin_amdgcn_mfma_f32_16x16x32_f16(af, whhf0[kt], acc0a, 0, 0, 0);
                    acc1a = __builtin_amdgcn_mfma_f32_16x16x32_f16(af, whhf1[kt], acc1a, 0, 0, 0);
                }
            }
        }
        const float4v g0 = acc0a + acc0b;
        const float4v g1 = acc1a + acc1b;

        // ---- regroup i,f,g,o per (row,unit) via per-wave LDS scratch ----
        float* gw = gs + wv * 256;
        if (lane < 32) {
            const int grow = (lane >> 4) * 4;
#pragma unroll
            for (int r = 0; r < 4; ++r) {
                gw[(grow + r) * 32 + col]      = g0[r];
                gw[(grow + r) * 32 + 16 + col] = g1[r];
            }
        }
        const float4v g4 = *(const float4v*)(gw + my_row * 32 + (lane & 7) * 4);

        const float i_s = sigm(g4[0]);
        const float f_s = sigm(g4[1]);
        const float g_t = tanhf(g4[2]);
        const float o_s = sigm(g4[3]);
        c_state = f_s * c_state + i_s * g_t;
        const float hn = o_s * tanhf(c_state);

        if (t == my_tstar)
            out[(rowbase + my_row) * HID + my_unit] = c_state;

        // ---- publish tagged h: one relaxed-agent b32 store, fire-and-forget ----
        const unsigned short hb = __builtin_bit_cast(unsigned short, (_Float16)hn);
        const unsigned tagged = ((unsigned)(t + 1) << 16) | (unsigned)hb;
        __hip_atomic_store(h_words + (size_t)(t & 1) * BATCH * HID
                                   + (rowbase + my_row) * HID + my_unit,
                           tagged, __ATOMIC_RELAXED, __HIP_MEMORY_SCOPE_AGENT);

        __syncthreads();   // protect hs tile before next iteration's staging
    }
}

extern "C" void kernel_launch(void* const* d_in, const int* in_sizes, int n_in,
                              void* d_out, int out_size, void* d_ws, size_t ws_size,
                              hipStream_t stream)
{
    const int*   ids  = (const int*)d_in[0];
    const int*   slen = (const int*)d_in[1];
    const float* emb  = (const float*)d_in[2];
    const float* wih  = (const float*)d_in[3];
    const float* whh  = (const float*)d_in[4];
    const float* bih  = (const float*)d_in[5];
    const float* bhh  = (const float*)d_in[6];
    float* out = (float*)d_out;

    unsigned* h_words = (unsigned*)d_ws;   // [2][128][512] tagged words = 512 KiB

    hipLaunchKernelGGL(lstm_persistent, dim3(256), dim3(256), 0, stream,
                       ids, slen, emb, wih, whh, bih, bhh, out, h_words);
}

// Round 3
// 2289.092 us; speedup vs baseline: 6.9478x; 1.3797x over previous
//
#include <hip/hip_runtime.h>

typedef _Float16 half8 __attribute__((ext_vector_type(8)));
typedef float float4v __attribute__((ext_vector_type(4)));
typedef unsigned long long u64;

#define BATCH 128
#define HID   512
#define DIN   128

// LDS: double-buffered h tile. Row stride 264 b32-words (528 halves) so the
// MFMA ds_read_b128 pattern (8*arow + 4*kq mod 32) lands 2-way max (free).
#define HW_STRIDE 264                        // b32 words per row
#define HBUF_WORDS (8 * HW_STRIDE)           // 2112 words per buffer
#define GOFF (2 * HBUF_WORDS * 4)            // 16896 B
#define LDS_BYTES (GOFF + 4 * 8 * 32 * 4)    // + per-wave gate scratch = 20992 B

__device__ inline half8 cvt8(float4v a, float4v b) {
    half8 r;
    r[0] = (_Float16)a[0]; r[1] = (_Float16)a[1];
    r[2] = (_Float16)a[2]; r[3] = (_Float16)a[3];
    r[4] = (_Float16)b[0]; r[5] = (_Float16)b[1];
    r[6] = (_Float16)b[2]; r[7] = (_Float16)b[3];
    return r;
}

// branch-free sigmoid / tanh on v_exp_f32 + v_rcp_f32 (abs err ~1e-7)
__device__ inline float sigm(float x) {
    return __builtin_amdgcn_rcpf(1.0f + __builtin_amdgcn_exp2f(-1.44269504f * x));
}
__device__ inline float tanh_fast(float x) { return 2.0f * sigm(2.0f * x) - 1.0f; }

// 16 teams x 16 CUs. Team owns rows [8t,8t+8); CU p owns units [32p,32p+32);
// wave w owns units [..+8w..). Weights VGPR-resident fp16 for the whole run.
// h handoff: tagged words ((t+1)<<16 | fp16(h)), double-buffered, relaxed
// AGENT atomics only (no L2 writeback/invalidate anywhere in the loop).
__global__ __launch_bounds__(256, 1)
void lstm_persistent(const int* __restrict__ ids,
                     const int* __restrict__ seq_len,
                     const float* __restrict__ emb,
                     const float* __restrict__ w_ih,
                     const float* __restrict__ w_hh,
                     const float* __restrict__ b_ih,
                     const float* __restrict__ b_hh,
                     float* __restrict__ out,
                     unsigned* __restrict__ h_words)   // [2][128][512] tagged
{
    __shared__ __align__(16) char smem[LDS_BYTES];
    unsigned* hsu = (unsigned*)smem;
    _Float16* hsh = (_Float16*)smem;
    float*    gs  = (float*)(smem + GOFF);

    const int tid  = threadIdx.x;
    const int lane = tid & 63;
    const int wv   = tid >> 6;
    const int team = blockIdx.x & 15;
    const int p    = blockIdx.x >> 4;
    const int rowbase   = team * 8;
    const int unit_base = p * 32 + wv * 8;

    const int col  = lane & 15;   // MFMA n / C col
    const int kq   = lane >> 4;   // MFMA k-quad
    const int arow = lane & 7;    // A row (rows 8..15 duplicate 0..7)
    const int my_row  = lane >> 3;
    const int my_unit = unit_base + (lane & 7);

    int tmax = 0, my_tstar = 0;
    for (int r = 0; r < 8; ++r) {
        int s  = seq_len[rowbase + r];
        int ts = (s > 0) ? (s - 1) : 0;
        if (r == my_row) my_tstar = ts;
        tmax = (ts > tmax) ? ts : tmax;
    }

    // ---- weight fragments -> VGPRs (fp32 -> fp16), once ----
    const int wrow0 = (col & 3) * HID + unit_base + (col >> 2);
    const int wrow1 = (col & 3) * HID + unit_base + 4 + (col >> 2);
    const float bias0 = b_ih[wrow0] + b_hh[wrow0];
    const float bias1 = b_ih[wrow1] + b_hh[wrow1];

    half8 whhf0[16], whhf1[16];
#pragma unroll
    for (int kt = 0; kt < 16; ++kt) {
        const float* s0 = w_hh + (size_t)wrow0 * HID + kt * 32 + kq * 8;
        const float* s1 = w_hh + (size_t)wrow1 * HID + kt * 32 + kq * 8;
        whhf0[kt] = cvt8(*(const float4v*)s0, *(const float4v*)(s0 + 4));
        whhf1[kt] = cvt8(*(const float4v*)s1, *(const float4v*)(s1 + 4));
    }
    half8 wihf0[4], wihf1[4];
#pragma unroll
    for (int kt = 0; kt < 4; ++kt) {
        const float* s0 = w_ih + (size_t)wrow0 * DIN + kt * 32 + kq * 8;
        const float* s1 = w_ih + (size_t)wrow1 * DIN + kt * 32 + kq * 8;
        wihf0[kt] = cvt8(*(const float4v*)s0, *(const float4v*)(s0 + 4));
        wihf1[kt] = cvt8(*(const float4v*)s1, *(const float4v*)(s1 + 4));
    }

    float c_state = 0.0f;
    const int crow = tid >> 5;    // poll/staging: row 0..7, 32 threads/row
    const int coff = tid & 31;    // thread polls b64 pairs {coff + 32j}

    // ---- preload x(0) fragments ----
    half8 xf[4];
    {
        const int id0 = ids[rowbase + arow];
        const float* xrow = emb + (size_t)id0 * DIN;
#pragma unroll
        for (int kt = 0; kt < 4; ++kt) {
            const float* s = xrow + kt * 32 + kq * 8;
            xf[kt] = cvt8(*(const float4v*)s, *(const float4v*)(s + 4));
        }
    }

    for (int t = 0; t <= tmax; ++t) {
        // issue next-step ids load early (clamped; overlaps everything)
        const int tn = (t < tmax) ? (t + 1) : t;
        const int id_next = ids[tn * BATCH + rowbase + arow];

        // ---- x MFMAs (h-independent; overlaps teammates' h stores) ----
        float4v acc0a = {bias0, bias0, bias0, bias0};
        float4v acc1a = {bias1, bias1, bias1, bias1};
        float4v acc0b = {0, 0, 0, 0}, acc1b = {0, 0, 0, 0};
#pragma unroll
        for (int kt = 0; kt < 4; ++kt) {
            if (kt & 1) {
                acc0b = __builtin_amdgcn_mfma_f32_16x16x32_f16(xf[kt], wihf0[kt], acc0b, 0, 0, 0);
                acc1b = __builtin_amdgcn_mfma_f32_16x16x32_f16(xf[kt], wihf1[kt], acc1b, 0, 0, 0);
            } else {
                acc0a = __builtin_amdgcn_mfma_f32_16x16x32_f16(xf[kt], wihf0[kt], acc0a, 0, 0, 0);
                acc1a = __builtin_amdgcn_mfma_f32_16x16x32_f16(xf[kt], wihf1[kt], acc1a, 0, 0, 0);
            }
        }

        const int bs = t & 1;    // LDS h-tile buffer for this step
        if (t > 0) {
            // ---- pending-only poll of teammates' tagged h (poll IS the load) ----
            const u64* rowp = (const u64*)(h_words
                + (size_t)((t + 1) & 1) * BATCH * HID + (rowbase + crow) * HID);
            const u64 tagmask = 0xFFFF0000FFFF0000ull;
            const u64 tagpat  = ((u64)t << 16) | ((u64)t << 48);
            u64 w[8];
            unsigned pending = 0xFF;
            int round = 0, guard = 0;
            do {
#pragma unroll
                for (int j = 0; j < 8; ++j) {
                    if (pending & (1u << j)) {
                        w[j] = __hip_atomic_load(rowp + coff + 32 * j,
                                                 __ATOMIC_RELAXED,
                                                 __HIP_MEMORY_SCOPE_AGENT);
                        if ((w[j] & tagmask) == tagpat) pending &= ~(1u << j);
                    }
                }
                if (!pending) break;
                if (++round >= 2) __builtin_amdgcn_s_sleep(1);
            } while (++guard < (1 << 22));

            // tag-strip + pack to LDS (conflict-free: banks = f(coff) unit-stride)
#pragma unroll
            for (int j = 0; j < 8; ++j) {
                unsigned packed = (unsigned)(w[j] & 0xFFFFu)
                                | ((unsigned)(w[j] >> 32) << 16);
                hsu[bs * HBUF_WORDS + crow * HW_STRIDE + coff + 32 * j] = packed;
            }
        }
        __syncthreads();   // the ONLY barrier per step (h-tile double-buffered)

        if (t > 0) {
            const _Float16* hb = hsh + bs * HBUF_WORDS * 2;
#pragma unroll
            for (int kt = 0; kt < 16; ++kt) {
                half8 af = *(const half8*)(hb + arow * (HW_STRIDE * 2) + kt * 32 + kq * 8);
                if (kt & 1) {
                    acc0b = __builtin_amdgcn_mfma_f32_16x16x32_f16(af, whhf0[kt], acc0b, 0, 0, 0);
                    acc1b = __builtin_amdgcn_mfma_f32_16x16x32_f16(af, whhf1[kt], acc1b, 0, 0, 0);
                } else {
                    acc0a = __builtin_amdgcn_mfma_f32_16x16x32_f16(af, whhf0[kt], acc0a, 0, 0, 0);
                    acc1a = __builtin_amdgcn_mfma_f32_16x16x32_f16(af, whhf1[kt], acc1a, 0, 0, 0);
                }
            }
        }
        const float4v g0 = acc0a + acc0b;
        const float4v g1 = acc1a + acc1b;

        // ---- regroup i,f,g,o per (row,unit) via per-wave LDS scratch ----
        float* gw = gs + wv * 256;
        if (lane < 32) {
            const int grow = (lane >> 4) * 4;
#pragma unroll
            for (int r = 0; r < 4; ++r) {
                gw[(grow + r) * 32 + col]      = g0[r];
                gw[(grow + r) * 32 + 16 + col] = g1[r];
            }
        }
        const float4v g4 = *(const float4v*)(gw + my_row * 32 + (lane & 7) * 4);

        const float i_s = sigm(g4[0]);
        const float f_s = sigm(g4[1]);
        const float g_t = tanh_fast(g4[2]);
        const float o_s = sigm(g4[3]);
        c_state = f_s * c_state + i_s * g_t;
        const float hn = o_s * tanh_fast(c_state);

        if (t == my_tstar)
            out[(rowbase + my_row) * HID + my_unit] = c_state;

        // ---- publish tagged h: one relaxed-agent b32 store, fire-and-forget ----
        const unsigned short hb16 = __builtin_bit_cast(unsigned short, (_Float16)hn);
        __hip_atomic_store(h_words + (size_t)(t & 1) * BATCH * HID
                                   + (rowbase + my_row) * HID + my_unit,
                           ((unsigned)(t + 1) << 16) | (unsigned)hb16,
                           __ATOMIC_RELAXED, __HIP_MEMORY_SCOPE_AGENT);

        // ---- prefetch x(t+1): emb loads issue here, land under next handoff ----
        {
            const float* xrow = emb + (size_t)id_next * DIN;
#pragma unroll
            for (int kt = 0; kt < 4; ++kt) {
                const float* s = xrow + kt * 32 + kq * 8;
                xf[kt] = cvt8(*(const float4v*)s, *(const float4v*)(s + 4));
            }
        }
    }
}

extern "C" void kernel_launch(void* const* d_in, const int* in_sizes, int n_in,
                              void* d_out, int out_size, void* d_ws, size_t ws_size,
                              hipStream_t stream)
{
    const int*   ids  = (const int*)d_in[0];
    const int*   slen = (const int*)d_in[1];
    const float* emb  = (const float*)d_in[2];
    const float* wih  = (const float*)d_in[3];
    const float* whh  = (const float*)d_in[4];
    const float* bih  = (const float*)d_in[5];
    const float* bhh  = (const float*)d_in[6];
    float* out = (float*)d_out;

    unsigned* h_words = (unsigned*)d_ws;   // [2][128][512] tagged words = 512 KiB

    hipLaunchKernelGGL(lstm_persistent, dim3(256), dim3(256), 0, stream,
                       ids, slen, emb, wih, whh, bih, bhh, out, h_words);
}